// Round 3
// baseline (377.084 us; speedup 1.0000x reference)
//
#include <hip/hip_runtime.h>
#include <math.h>

#define SEQ 2048
#define EMB 2048

typedef _Float16 f16;
typedef unsigned short ushort_t;
typedef __attribute__((ext_vector_type(2))) _Float16 f16x2;
typedef __attribute__((ext_vector_type(4))) _Float16 f16x4;
typedef __attribute__((ext_vector_type(8))) _Float16 f16x8;
typedef __attribute__((ext_vector_type(4))) float f32x4;
typedef __attribute__((ext_vector_type(16))) float f32x16;
typedef __attribute__((ext_vector_type(8))) short bf16x8;
typedef __attribute__((ext_vector_type(4))) unsigned short us4;
typedef __attribute__((ext_vector_type(8))) unsigned short us8;
typedef __attribute__((ext_vector_type(4))) unsigned int uint4v;

// async global->LDS, 16B per lane; LDS dest is lane-contiguous from lane0's ptr
__device__ __forceinline__ void gload16(const void* g, void* l) {
  __builtin_amdgcn_global_load_lds((const __attribute__((address_space(1))) unsigned int*)g,
                                   (__attribute__((address_space(3))) unsigned int*)l, 16, 0, 0);
}

__device__ __forceinline__ ushort_t f32_to_bf16(float f) {
  unsigned int u = __builtin_bit_cast(unsigned int, f);
  u += 0x7FFFu + ((u >> 16) & 1u);
  return (ushort_t)(u >> 16);
}

// packed f32x2 -> bf16x2 in one VALU op (RNE)
__device__ __forceinline__ unsigned cvt_pk_bf16_2(float lo, float hi) {
  unsigned r;
  asm("v_cvt_pk_bf16_f32 %0, %1, %2" : "=v"(r) : "v"(lo), "v"(hi));
  return r;
}

// ---------------- fp32 -> fp16 conversion, 5 tensors in one launch ----------------
__global__ __launch_bounds__(256) void cvt5_kernel(const float* __restrict__ i0,
                                                   const float* __restrict__ i1,
                                                   const float* __restrict__ i2,
                                                   const float* __restrict__ i3,
                                                   const float* __restrict__ i4,
                                                   f16* __restrict__ o0, f16* __restrict__ o1,
                                                   f16* __restrict__ o2, f16* __restrict__ o3,
                                                   f16* __restrict__ o4) {
  int b = blockIdx.x;
  int z = b >> 12;
  const float* in = (z == 0) ? i0 : (z == 1) ? i1 : (z == 2) ? i2 : (z == 3) ? i3 : i4;
  f16* out = (z == 0) ? o0 : (z == 1) ? o1 : (z == 2) ? o2 : (z == 3) ? o3 : o4;
  int i = ((b & 4095) * 256 + threadIdx.x) * 4;
  f32x4 v = *(const f32x4*)(in + i);
  *(f16x4*)(out + i) = __builtin_convertvector(v, f16x4);
}

// ---------------- RoPE tables (double precision, matches numpy) ----------------
__global__ __launch_bounds__(256) void rope_table_kernel(float* __restrict__ cosT,
                                                         float* __restrict__ sinT) {
  int id = blockIdx.x * 256 + threadIdx.x;
  int t = id >> 5, i = id & 31;
  double inv = pow(10000.0, -(double)i / 32.0);
  double ang = (double)t * inv;
  cosT[id] = (float)cos(ang);
  sinT[id] = (float)sin(ang);
}

// ---------------- RoPE apply on q (fused scale) and k, one launch ----------------
__global__ __launch_bounds__(256) void rope2_kernel(f16* __restrict__ q, f16* __restrict__ k,
                                                    const float* __restrict__ cosT,
                                                    const float* __restrict__ sinT) {
  f16* x = blockIdx.y ? k : q;
  const float scale = blockIdx.y ? 1.0f : 16.3222307f;  // sqrt(128)*log2(e) folded into q
  int id = blockIdx.x * 256 + threadIdx.x;
  int i = id & 31;
  int nh2 = (id >> 5) & 31;
  int t = id >> 10;
  float c = cosT[(t << 5) + i], s = sinT[(t << 5) + i];
  int base = t * EMB + nh2 * 64 + 2 * i;
  f16x2 p = *(f16x2*)(x + base);
  float xr = (float)p.x, xi = (float)p.y;
  f16x2 o;
  o.x = (f16)((xr * c - xi * s) * scale);
  o.y = (f16)((xr * s + xi * c) * scale);
  *(f16x2*)(x + base) = o;
}

// ---------------- Fused projection GEMM, BK=32, swizzled LDS ----------------
// z=0->q f16, z=1->k f16, z=2->v bf16 fragment-tiled vbT for 32x32x16 PV:
// vbT index for V[t][h*128+d] (kb=t>>6, kc=(t>>4)&3, hi8=(t>>3)&1, j=t&7, dt=d>>5, dr=d&31):
//   (((h*32+kb)*4+kc)*4+dt)*512 + (hi8*32+dr)*8 + j
__global__ __launch_bounds__(256, 3) void proj_gemm_kernel(
    const f16* __restrict__ A, const f16* __restrict__ B0, const f16* __restrict__ B1,
    const f16* __restrict__ B2, f16* __restrict__ qout, f16* __restrict__ kout,
    ushort_t* __restrict__ vtout) {
  const int z = blockIdx.z;
  const f16* __restrict__ B = (z == 0) ? B0 : ((z == 1) ? B1 : B2);
  __shared__ f16 As[128 * 32];
  __shared__ f16 Bs[128 * 32];
  const int tid = threadIdx.x;
  const int wave = tid >> 6, lane = tid & 63;
  const int l16 = lane & 15, quad = lane >> 4;
  const int wm = (wave >> 1) << 6, wn = (wave & 1) << 6;
  const int bm = blockIdx.y << 7, bn = blockIdx.x << 7;

  const int swg = ((lane & 3) ^ ((lane >> 3) & 3)) * 8;
  const f16* Ag = A + (size_t)(bm + wave * 32 + (lane >> 2)) * EMB + swg;
  const f16* Bg = B + (size_t)(bn + wave * 32 + (lane >> 2)) * EMB + swg;
  f16* Asl = &As[wave * 1024 + lane * 8];
  f16* Bsl = &Bs[wave * 1024 + lane * 8];

  const int swr = (quad ^ ((l16 >> 1) & 3)) * 8;
  int aoff[4], boff[4];
#pragma unroll
  for (int i = 0; i < 4; i++) {
    aoff[i] = (wm + i * 16 + l16) * 32 + swr;
    boff[i] = (wn + i * 16 + l16) * 32 + swr;
  }

  f32x4 acc[4][4];
#pragma unroll
  for (int i = 0; i < 4; i++)
#pragma unroll
    for (int j = 0; j < 4; j++) acc[i][j] = (f32x4){0.f, 0.f, 0.f, 0.f};

  for (int k0 = 0; k0 < EMB; k0 += 32) {
    __syncthreads();
    gload16(Ag + k0, Asl);
    gload16(Ag + (size_t)16 * EMB + k0, Asl + 512);
    gload16(Bg + k0, Bsl);
    gload16(Bg + (size_t)16 * EMB + k0, Bsl + 512);
    __syncthreads();
    f16x8 af[4], bf[4];
#pragma unroll
    for (int mi = 0; mi < 4; mi++) af[mi] = *(const f16x8*)&As[aoff[mi]];
#pragma unroll
    for (int ni = 0; ni < 4; ni++) bf[ni] = *(const f16x8*)&Bs[boff[ni]];
#pragma unroll
    for (int mi = 0; mi < 4; mi++)
#pragma unroll
      for (int ni = 0; ni < 4; ni++)
        acc[mi][ni] = __builtin_amdgcn_mfma_f32_16x16x32_f16(af[mi], bf[ni], acc[mi][ni], 0, 0, 0);
  }

#pragma unroll
  for (int mi = 0; mi < 4; mi++) {
#pragma unroll
    for (int ni = 0; ni < 4; ni++) {
      int row0 = bm + wm + mi * 16 + quad * 4;  // C/D: col=l16, row=quad*4+reg
      int col = bn + wn + ni * 16 + l16;
      if (z == 2) {
        us4 o;
#pragma unroll
        for (int rg = 0; rg < 4; rg++) o[rg] = f32_to_bf16(acc[mi][ni][rg]);
        int hidx = col >> 7, d = col & 127, t = row0;  // t..t+3 share all bits above t&7
        size_t idx = ((((size_t)hidx * 32 + (t >> 6)) * 4 + ((t >> 4) & 3)) * 4 + (d >> 5)) * 512 +
                     (((t >> 3) & 1) * 32 + (d & 31)) * 8 + (t & 7);
        *(us4*)&vtout[idx] = o;
      } else {
        f16* Co = (z == 0) ? qout : kout;
#pragma unroll
        for (int rg = 0; rg < 4; rg++)
          Co[(size_t)(row0 + rg) * EMB + col] = (f16)acc[mi][ni][rg];
      }
    }
  }
}

// ---------------- Output GEMM: C = attn * wout^T, f32 out, 128x64 tiles, BK=32 ----------
__global__ __launch_bounds__(256, 2) void out_gemm_kernel(const f16* __restrict__ A,
                                                          const f16* __restrict__ B,
                                                          float* __restrict__ C) {
  __shared__ f16 As[128 * 32];
  __shared__ f16 Bs[64 * 32];
  const int tid = threadIdx.x;
  const int wave = tid >> 6, lane = tid & 63;
  const int l16 = lane & 15, quad = lane >> 4;
  const int wm = (wave >> 1) << 6, wn = (wave & 1) << 5;
  const int bm = blockIdx.y << 7, bn = blockIdx.x << 6;

  const int swg = ((lane & 3) ^ ((lane >> 3) & 3)) * 8;
  const f16* Ag = A + (size_t)(bm + wave * 32 + (lane >> 2)) * EMB + swg;
  const f16* Bg = B + (size_t)(bn + wave * 16 + (lane >> 2)) * EMB + swg;
  f16* Asl = &As[wave * 1024 + lane * 8];
  f16* Bsl = &Bs[wave * 512 + lane * 8];

  const int swr = (quad ^ ((l16 >> 1) & 3)) * 8;
  int aoff[4], boff[2];
#pragma unroll
  for (int i = 0; i < 4; i++) aoff[i] = (wm + i * 16 + l16) * 32 + swr;
#pragma unroll
  for (int i = 0; i < 2; i++) boff[i] = (wn + i * 16 + l16) * 32 + swr;

  f32x4 acc[4][2];
#pragma unroll
  for (int i = 0; i < 4; i++)
#pragma unroll
    for (int j = 0; j < 2; j++) acc[i][j] = (f32x4){0.f, 0.f, 0.f, 0.f};

  for (int k0 = 0; k0 < EMB; k0 += 32) {
    __syncthreads();
    gload16(Ag + k0, Asl);
    gload16(Ag + (size_t)16 * EMB + k0, Asl + 512);
    gload16(Bg + k0, Bsl);
    __syncthreads();
    f16x8 af[4], bf[2];
#pragma unroll
    for (int mi = 0; mi < 4; mi++) af[mi] = *(const f16x8*)&As[aoff[mi]];
#pragma unroll
    for (int ni = 0; ni < 2; ni++) bf[ni] = *(const f16x8*)&Bs[boff[ni]];
#pragma unroll
    for (int mi = 0; mi < 4; mi++)
#pragma unroll
      for (int ni = 0; ni < 2; ni++)
        acc[mi][ni] = __builtin_amdgcn_mfma_f32_16x16x32_f16(af[mi], bf[ni], acc[mi][ni], 0, 0, 0);
  }

#pragma unroll
  for (int mi = 0; mi < 4; mi++) {
#pragma unroll
    for (int ni = 0; ni < 2; ni++) {
      int row0 = bm + wm + mi * 16 + quad * 4;
      int col = bn + wn + ni * 16 + l16;
#pragma unroll
      for (int rg = 0; rg < 4; rg++)
        C[(size_t)(row0 + rg) * EMB + col] = acc[mi][ni][rg];
    }
  }
}

// ---------------- Differential attention v7: 8 waves, key-split ----------------
// 512 threads, 8 waves: wave = ks*4 + hh*2 + qs. Each wave: 32 q-rows (qs), one
// half (hh), one 32-key half (ks) of each 64-key tile. Grid (16,32)=512 blocks,
// 2/CU (64.5 KB LDS) -> 16 waves/CU (4/SIMD at VGPR<=128).
// Per wave-step: 4 QK MFMA + 16 exp2 + 8 PV MFMA + 12 ds_read_b128 -> half of
// v6's serial chain, with 2x the waves to overlap VALU/DS/MFMA pipes.
// ks-halves accumulate independent partial O/lsum (valid: fixed softmax bias,
// no running max) and combine through LDS in a 3-barrier epilogue.
// Ks tile T=hh*8+kb*4+c: entry[l*8+j] = K[kb*32+(l&31)][hh*64+c*16+(l>>5)*8+j]
// Vt tile T=kc*4+dt:     entry[l*8+j] = V[kc*16+(l>>5)*8+j][dt*32+(l&31)]
__global__ __launch_bounds__(512, 4) void diff_attn_v7(
    const f16* __restrict__ qb, const f16* __restrict__ kb, const ushort_t* __restrict__ vbT,
    const float* __restrict__ lq1, const float* __restrict__ lq2,
    const float* __restrict__ lk1, const float* __restrict__ lk2,
    const float* __restrict__ subw, f16* __restrict__ attnb) {
  const int h = blockIdx.x;  // head fastest -> heads stay L2-resident per XCD
  const int qblk = blockIdx.y;
  const int tid = threadIdx.x;
  const int wave = tid >> 6, lane = tid & 63;
  const int l32 = lane & 31, hi = lane >> 5;
  const int ks = wave >> 2, hh = (wave >> 1) & 1, qs = wave & 1;

  __shared__ __align__(16) char smem[65536];  // Ks[2] 32KB | Vt[2] 32KB; epilogue: Obuf
  __shared__ float lsb[128];                  // ks=1 partial denominators [hh][qs][q]
  f16* Ks0 = (f16*)smem;                       // buf b at Ks0 + b*8192
  ushort_t* Vt0 = (ushort_t*)(smem + 32768);   // buf b at Vt0 + b*8192

  // ---- Q B-frags (q pre-scaled by sqrt(128)*log2e at rope): col=q=l32, k=hi*8+j ----
  const int qrow0 = qblk * 64 + qs * 32;
  f16x8 qf[4];
#pragma unroll
  for (int c = 0; c < 4; c++)
    qf[c] = *(const f16x8*)(qb + (size_t)(qrow0 + l32) * EMB + h * 128 + hh * 64 + c * 16 + hi * 8);

  f32x16 O[4];  // [dim-tile]; col=q=l32, row=(r&3)+8*(r>>2)+4*hi = dim within tile
#pragma unroll
  for (int dt = 0; dt < 4; dt++)
#pragma unroll
    for (int s2 = 0; s2 < 16; s2++) O[dt][s2] = 0.f;
  float lsum = 0.f;

  // ---- staging source addresses (waves 0-3: K tiles w*4+j2; waves 4-7: V tiles) ----
  const bool isK = (wave < 4);
  const f16* kgp =
      kb + (size_t)((wave & 1) * 32 + l32) * EMB + h * 128 + ((wave >> 1) & 1) * 64 + hi * 8;
  const ushort_t* vgp = vbT + (size_t)h * 262144 + (size_t)(wave & 3) * 2048 + lane * 8;

  auto stage = [&](int buf, int it) {
    if (isK) {
      const f16* src = kgp + (size_t)it * (64 * EMB);
      f16* dst = Ks0 + buf * 8192 + wave * 2048;
#pragma unroll
      for (int j2 = 0; j2 < 4; j2++) gload16(src + j2 * 16, dst + j2 * 512);
    } else {
      const ushort_t* src = vgp + (size_t)it * 8192;
      ushort_t* dst = Vt0 + buf * 8192 + (wave - 4) * 2048;
#pragma unroll
      for (int j2 = 0; j2 < 4; j2++) gload16(src + j2 * 512, dst + j2 * 512);
    }
  };

  // ---- initial tile 0 into buf 0 ----
  stage(0, 0);
  __syncthreads();

  auto step = [&](int cbuf, int nit) {
    if (nit < 32) stage(cbuf ^ 1, nit);  // async, lands before next barrier

    const f16* KsC = Ks0 + cbuf * 8192;
    const ushort_t* VtC = Vt0 + cbuf * 8192;

    // ---- S^T = K·Q^T for this wave's 32-key half (ks) ----
    f32x16 acc;
#pragma unroll
    for (int s2 = 0; s2 < 16; s2++) acc[s2] = -28.8539008f;  // softmax bias in C-init
#pragma unroll
    for (int c = 0; c < 4; c++) {
      f16x8 kf = *(const f16x8*)&KsC[(hh * 8 + ks * 4 + c) * 512 + lane * 8];
      acc = __builtin_amdgcn_mfma_f32_32x32x16_f16(kf, qf[c], acc, 0, 0, 0);
    }
    float p[16];
#pragma unroll
    for (int s2 = 0; s2 < 16; s2++) p[s2] = __builtin_exp2f(acc[s2]);
    lsum += (((p[0] + p[1]) + (p[2] + p[3])) + ((p[4] + p[5]) + (p[6] + p[7]))) +
            (((p[8] + p[9]) + (p[10] + p[11])) + ((p[12] + p[13]) + (p[14] + p[15])));
    // key = (s&3)+8*(s>>2)+4*hi; c2=s>>3 selects 16-key chunk; build PV B-frags in regs
    bf16x8 pf[2];
#pragma unroll
    for (int c2 = 0; c2 < 2; c2++) {
      unsigned w0 = cvt_pk_bf16_2(p[8 * c2 + 0], p[8 * c2 + 1]);
      unsigned w1 = cvt_pk_bf16_2(p[8 * c2 + 2], p[8 * c2 + 3]);
      unsigned w2 = cvt_pk_bf16_2(p[8 * c2 + 4], p[8 * c2 + 5]);
      unsigned w3 = cvt_pk_bf16_2(p[8 * c2 + 6], p[8 * c2 + 7]);
      asm("v_permlane32_swap_b32 %0, %1" : "+v"(w0), "+v"(w2));
      asm("v_permlane32_swap_b32 %0, %1" : "+v"(w1), "+v"(w3));
      uint4v pw;
      pw.x = w0; pw.y = w1; pw.z = w2; pw.w = w3;
      pf[c2] = __builtin_bit_cast(bf16x8, pw);
    }

    // ---- O^T += V * P over this wave's two 16-key chunks ----
    __builtin_amdgcn_s_setprio(1);
#pragma unroll
    for (int c2 = 0; c2 < 2; c2++) {
#pragma unroll
      for (int dt = 0; dt < 4; dt++) {
        bf16x8 vf = *(const bf16x8*)&VtC[((ks * 2 + c2) * 4 + dt) * 512 + lane * 8];
        O[dt] = __builtin_amdgcn_mfma_f32_32x32x16_bf16(vf, pf[c2], O[dt], 0, 0, 0);
      }
    }
    __builtin_amdgcn_s_setprio(0);
    __syncthreads();
  };

  for (int it = 0; it < 32; it += 2) {
    step(0, it + 1);
    step(1, it + 2);
  }

  // ---- lambda ----
  float d1 = 0.f, d2 = 0.f;
  for (int i = 0; i < 64; i++) {
    d1 += lq1[i] * lk1[i];
    d2 += lq2[i] * lk2[i];
  }
  const float lam = __expf(d1) - __expf(d2) + 0.783605767f;

  // ---- this wave's partial denominator (hi/lo lanes cover disjoint keys) ----
  const float s_part = lsum + __shfl_xor(lsum, 32);

  float* Obuf = (float*)smem;  // 16384 floats; quadrant (hh*2+qs): 4096 floats

  // ---- phase 1: ks=1 waves publish partial O and lsum ----
  if (ks == 1) {
    float* ob = Obuf + (hh * 2 + qs) * 4096;
#pragma unroll
    for (int dt = 0; dt < 4; dt++)
#pragma unroll
      for (int rq = 0; rq < 4; rq++) {
        f32x4 v;
#pragma unroll
        for (int rg = 0; rg < 4; rg++) v[rg] = O[dt][rq * 4 + rg];
        *(f32x4*)&ob[(dt * 4 + rq) * 256 + lane * 4] = v;
      }
    lsb[(hh * 2 + qs) * 32 + l32] = s_part;
  }
  __syncthreads();

  // ---- phase 2: ks=0 waves merge ks-halves ----
  float inv_ = 0.f;
  if (ks == 0) {
    const float* ob = Obuf + (hh * 2 + qs) * 4096;
#pragma unroll
    for (int dt = 0; dt < 4; dt++)
#pragma unroll
      for (int rq = 0; rq < 4; rq++) {
        f32x4 v1 = *(const f32x4*)&ob[(dt * 4 + rq) * 256 + lane * 4];
#pragma unroll
        for (int rg = 0; rg < 4; rg++) O[dt][rq * 4 + rg] += v1[rg];
      }
    const float s = s_part + lsb[(hh * 2 + qs) * 32 + l32];
    inv_ = (hh == 0) ? (1.f / s) : (lam / s);
  }
  __syncthreads();

  // ---- phase 3: hh=1 (ks=0) writes scaled O into lower 32KB ----
  if (ks == 0 && hh == 1) {
#pragma unroll
    for (int dt = 0; dt < 4; dt++)
#pragma unroll
      for (int rq = 0; rq < 4; rq++) {
        f32x4 v;
#pragma unroll
        for (int rg = 0; rg < 4; rg++) v[rg] = O[dt][rq * 4 + rg] * inv_;
        *(f32x4*)&Obuf[((qs * 4 + dt) * 4 + rq) * 256 + lane * 4] = v;
      }
  }
  __syncthreads();

  // ---- phase 4: hh=0 (ks=0) computes diff, RMS-norm, store ----
  if (ks == 0 && hh == 0) {
    float a[4][16];
    float ms = 0.f;
#pragma unroll
    for (int dt = 0; dt < 4; dt++)
#pragma unroll
      for (int rq = 0; rq < 4; rq++) {
        f32x4 o1 = *(const f32x4*)&Obuf[((qs * 4 + dt) * 4 + rq) * 256 + lane * 4];
#pragma unroll
        for (int rg = 0; rg < 4; rg++) {
          float v = O[dt][rq * 4 + rg] * inv_ - o1[rg];
          a[dt][rq * 4 + rg] = v;
          ms += v * v;
        }
      }
    ms += __shfl_xor(ms, 32);
    const float rms = rsqrtf(ms * (1.f / 128.f) + 1e-5f);
    const int t_g = qrow0 + l32;
#pragma unroll
    for (int dt = 0; dt < 4; dt++)
#pragma unroll
      for (int rq = 0; rq < 4; rq++) {
        f32x4 sw = *(const f32x4*)(subw + dt * 32 + rq * 8 + hi * 4);
        f16x4 o;
#pragma unroll
        for (int rg = 0; rg < 4; rg++) o[rg] = (f16)(a[dt][rq * 4 + rg] * rms * sw[rg]);
        *(f16x4*)(attnb + (size_t)t_g * EMB + h * 128 + dt * 32 + rq * 8 + hi * 4) = o;
      }
  }
}

// ---------------- launcher ----------------
extern "C" void kernel_launch(void* const* d_in, const int* in_sizes, int n_in,
                              void* d_out, int out_size, void* d_ws, size_t ws_size,
                              hipStream_t stream) {
  const float* x    = (const float*)d_in[0];
  const float* wq   = (const float*)d_in[1];
  const float* wk   = (const float*)d_in[2];
  const float* wv   = (const float*)d_in[3];
  const float* wout = (const float*)d_in[4];
  const float* lq1  = (const float*)d_in[5];
  const float* lq2  = (const float*)d_in[6];
  const float* lk1  = (const float*)d_in[7];
  const float* lk2  = (const float*)d_in[8];
  const float* subw = (const float*)d_in[9];
  float* out = (float*)d_out;

  char* ws = (char*)d_ws;
  const size_t MB = 1024 * 1024;
  f16* xb    = (f16*)(ws + 0 * MB);
  f16* wqb   = (f16*)(ws + 8 * MB);
  f16* wkb   = (f16*)(ws + 16 * MB);
  f16* wvb   = (f16*)(ws + 24 * MB);
  f16* woutb = (f16*)(ws + 32 * MB);
  f16* qb    = (f16*)(ws + 40 * MB);
  f16* kb    = (f16*)(ws + 48 * MB);
  ushort_t* vbT = (ushort_t*)(ws + 56 * MB);  // bf16, 32x32-fragment-tiled per head
  f16* attnb = (f16*)(ws + 64 * MB);
  float* cosT = (float*)(ws + 72 * MB);
  float* sinT = (float*)(ws + 72 * MB + 262144);

  dim3 b256(256);
  cvt5_kernel<<<5 * 4096, b256, 0, stream>>>(x, wq, wk, wv, wout, xb, wqb, wkb, wvb, woutb);
  rope_table_kernel<<<256, b256, 0, stream>>>(cosT, sinT);

  proj_gemm_kernel<<<dim3(16, 16, 3), b256, 0, stream>>>(xb, wqb, wkb, wvb, qb, kb, vbT);

  rope2_kernel<<<dim3(8192, 2), b256, 0, stream>>>(qb, kb, cosT, sinT);

  diff_attn_v7<<<dim3(16, 32), dim3(512), 0, stream>>>(qb, kb, vbT, lq1, lq2, lk1, lk2, subw,
                                                       attnb);

  out_gemm_kernel<<<dim3(32, 16), b256, 0, stream>>>(attnb, woutb, out);
}

// Round 4
// 304.070 us; speedup vs baseline: 1.2401x; 1.2401x over previous
//
#include <hip/hip_runtime.h>
#include <math.h>

#define SEQ 2048
#define EMB 2048

typedef _Float16 f16;
typedef unsigned short ushort_t;
typedef __attribute__((ext_vector_type(2))) _Float16 f16x2;
typedef __attribute__((ext_vector_type(4))) _Float16 f16x4;
typedef __attribute__((ext_vector_type(8))) _Float16 f16x8;
typedef __attribute__((ext_vector_type(4))) float f32x4;
typedef __attribute__((ext_vector_type(16))) float f32x16;
typedef __attribute__((ext_vector_type(8))) short bf16x8;
typedef __attribute__((ext_vector_type(4))) unsigned short us4;
typedef __attribute__((ext_vector_type(8))) unsigned short us8;
typedef __attribute__((ext_vector_type(4))) unsigned int uint4v;

// async global->LDS, 16B per lane; LDS dest is lane-contiguous from lane0's ptr
__device__ __forceinline__ void gload16(const void* g, void* l) {
  __builtin_amdgcn_global_load_lds((const __attribute__((address_space(1))) unsigned int*)g,
                                   (__attribute__((address_space(3))) unsigned int*)l, 16, 0, 0);
}

__device__ __forceinline__ ushort_t f32_to_bf16(float f) {
  unsigned int u = __builtin_bit_cast(unsigned int, f);
  u += 0x7FFFu + ((u >> 16) & 1u);
  return (ushort_t)(u >> 16);
}

// packed f32x2 -> bf16x2 in one VALU op (RNE)
__device__ __forceinline__ unsigned cvt_pk_bf16_2(float lo, float hi) {
  unsigned r;
  asm("v_cvt_pk_bf16_f32 %0, %1, %2" : "=v"(r) : "v"(lo), "v"(hi));
  return r;
}

// ---------------- fp32 -> fp16 conversion, 5 tensors in one launch ----------------
__global__ __launch_bounds__(256) void cvt5_kernel(const float* __restrict__ i0,
                                                   const float* __restrict__ i1,
                                                   const float* __restrict__ i2,
                                                   const float* __restrict__ i3,
                                                   const float* __restrict__ i4,
                                                   f16* __restrict__ o0, f16* __restrict__ o1,
                                                   f16* __restrict__ o2, f16* __restrict__ o3,
                                                   f16* __restrict__ o4) {
  int b = blockIdx.x;
  int z = b >> 12;
  const float* in = (z == 0) ? i0 : (z == 1) ? i1 : (z == 2) ? i2 : (z == 3) ? i3 : i4;
  f16* out = (z == 0) ? o0 : (z == 1) ? o1 : (z == 2) ? o2 : (z == 3) ? o3 : o4;
  int i = ((b & 4095) * 256 + threadIdx.x) * 4;
  f32x4 v = *(const f32x4*)(in + i);
  *(f16x4*)(out + i) = __builtin_convertvector(v, f16x4);
}

// ---------------- RoPE tables (double precision, matches numpy) ----------------
__global__ __launch_bounds__(256) void rope_table_kernel(float* __restrict__ cosT,
                                                         float* __restrict__ sinT) {
  int id = blockIdx.x * 256 + threadIdx.x;
  int t = id >> 5, i = id & 31;
  double inv = pow(10000.0, -(double)i / 32.0);
  double ang = (double)t * inv;
  cosT[id] = (float)cos(ang);
  sinT[id] = (float)sin(ang);
}

// ---------------- RoPE apply on q (fused scale) and k, one launch ----------------
__global__ __launch_bounds__(256) void rope2_kernel(f16* __restrict__ q, f16* __restrict__ k,
                                                    const float* __restrict__ cosT,
                                                    const float* __restrict__ sinT) {
  f16* x = blockIdx.y ? k : q;
  const float scale = blockIdx.y ? 1.0f : 16.3222307f;  // sqrt(128)*log2(e) folded into q
  int id = blockIdx.x * 256 + threadIdx.x;
  int i = id & 31;
  int nh2 = (id >> 5) & 31;
  int t = id >> 10;
  float c = cosT[(t << 5) + i], s = sinT[(t << 5) + i];
  int base = t * EMB + nh2 * 64 + 2 * i;
  f16x2 p = *(f16x2*)(x + base);
  float xr = (float)p.x, xi = (float)p.y;
  f16x2 o;
  o.x = (f16)((xr * c - xi * s) * scale);
  o.y = (f16)((xr * s + xi * c) * scale);
  *(f16x2*)(x + base) = o;
}

// ---------------- Fused projection GEMM, BK=32, swizzled LDS ----------------
// z=0->q f16, z=1->k f16, z=2->v bf16 fragment-tiled vbT for 32x32x16 PV:
// vbT index for V[t][h*128+d] (kb=t>>6, kc=(t>>4)&3, hi8=(t>>3)&1, j=t&7, dt=d>>5, dr=d&31):
//   (((h*32+kb)*4+kc)*4+dt)*512 + (hi8*32+dr)*8 + j
__global__ __launch_bounds__(256, 3) void proj_gemm_kernel(
    const f16* __restrict__ A, const f16* __restrict__ B0, const f16* __restrict__ B1,
    const f16* __restrict__ B2, f16* __restrict__ qout, f16* __restrict__ kout,
    ushort_t* __restrict__ vtout) {
  const int z = blockIdx.z;
  const f16* __restrict__ B = (z == 0) ? B0 : ((z == 1) ? B1 : B2);
  __shared__ f16 As[128 * 32];
  __shared__ f16 Bs[128 * 32];
  const int tid = threadIdx.x;
  const int wave = tid >> 6, lane = tid & 63;
  const int l16 = lane & 15, quad = lane >> 4;
  const int wm = (wave >> 1) << 6, wn = (wave & 1) << 6;
  const int bm = blockIdx.y << 7, bn = blockIdx.x << 7;

  const int swg = ((lane & 3) ^ ((lane >> 3) & 3)) * 8;
  const f16* Ag = A + (size_t)(bm + wave * 32 + (lane >> 2)) * EMB + swg;
  const f16* Bg = B + (size_t)(bn + wave * 32 + (lane >> 2)) * EMB + swg;
  f16* Asl = &As[wave * 1024 + lane * 8];
  f16* Bsl = &Bs[wave * 1024 + lane * 8];

  const int swr = (quad ^ ((l16 >> 1) & 3)) * 8;
  int aoff[4], boff[4];
#pragma unroll
  for (int i = 0; i < 4; i++) {
    aoff[i] = (wm + i * 16 + l16) * 32 + swr;
    boff[i] = (wn + i * 16 + l16) * 32 + swr;
  }

  f32x4 acc[4][4];
#pragma unroll
  for (int i = 0; i < 4; i++)
#pragma unroll
    for (int j = 0; j < 4; j++) acc[i][j] = (f32x4){0.f, 0.f, 0.f, 0.f};

  for (int k0 = 0; k0 < EMB; k0 += 32) {
    __syncthreads();
    gload16(Ag + k0, Asl);
    gload16(Ag + (size_t)16 * EMB + k0, Asl + 512);
    gload16(Bg + k0, Bsl);
    gload16(Bg + (size_t)16 * EMB + k0, Bsl + 512);
    __syncthreads();
    f16x8 af[4], bf[4];
#pragma unroll
    for (int mi = 0; mi < 4; mi++) af[mi] = *(const f16x8*)&As[aoff[mi]];
#pragma unroll
    for (int ni = 0; ni < 4; ni++) bf[ni] = *(const f16x8*)&Bs[boff[ni]];
#pragma unroll
    for (int mi = 0; mi < 4; mi++)
#pragma unroll
      for (int ni = 0; ni < 4; ni++)
        acc[mi][ni] = __builtin_amdgcn_mfma_f32_16x16x32_f16(af[mi], bf[ni], acc[mi][ni], 0, 0, 0);
  }

#pragma unroll
  for (int mi = 0; mi < 4; mi++) {
#pragma unroll
    for (int ni = 0; ni < 4; ni++) {
      int row0 = bm + wm + mi * 16 + quad * 4;  // C/D: col=l16, row=quad*4+reg
      int col = bn + wn + ni * 16 + l16;
      if (z == 2) {
        us4 o;
#pragma unroll
        for (int rg = 0; rg < 4; rg++) o[rg] = f32_to_bf16(acc[mi][ni][rg]);
        int hidx = col >> 7, d = col & 127, t = row0;  // t..t+3 share all bits above t&7
        size_t idx = ((((size_t)hidx * 32 + (t >> 6)) * 4 + ((t >> 4) & 3)) * 4 + (d >> 5)) * 512 +
                     (((t >> 3) & 1) * 32 + (d & 31)) * 8 + (t & 7);
        *(us4*)&vtout[idx] = o;
      } else {
        f16* Co = (z == 0) ? qout : kout;
#pragma unroll
        for (int rg = 0; rg < 4; rg++)
          Co[(size_t)(row0 + rg) * EMB + col] = (f16)acc[mi][ni][rg];
      }
    }
  }
}

// ---------------- Output GEMM: C = attn * wout^T, f32 out, 128x64 tiles, BK=32 ----------
__global__ __launch_bounds__(256, 2) void out_gemm_kernel(const f16* __restrict__ A,
                                                          const f16* __restrict__ B,
                                                          float* __restrict__ C) {
  __shared__ f16 As[128 * 32];
  __shared__ f16 Bs[64 * 32];
  const int tid = threadIdx.x;
  const int wave = tid >> 6, lane = tid & 63;
  const int l16 = lane & 15, quad = lane >> 4;
  const int wm = (wave >> 1) << 6, wn = (wave & 1) << 5;
  const int bm = blockIdx.y << 7, bn = blockIdx.x << 6;

  const int swg = ((lane & 3) ^ ((lane >> 3) & 3)) * 8;
  const f16* Ag = A + (size_t)(bm + wave * 32 + (lane >> 2)) * EMB + swg;
  const f16* Bg = B + (size_t)(bn + wave * 16 + (lane >> 2)) * EMB + swg;
  f16* Asl = &As[wave * 1024 + lane * 8];
  f16* Bsl = &Bs[wave * 512 + lane * 8];

  const int swr = (quad ^ ((l16 >> 1) & 3)) * 8;
  int aoff[4], boff[2];
#pragma unroll
  for (int i = 0; i < 4; i++) aoff[i] = (wm + i * 16 + l16) * 32 + swr;
#pragma unroll
  for (int i = 0; i < 2; i++) boff[i] = (wn + i * 16 + l16) * 32 + swr;

  f32x4 acc[4][2];
#pragma unroll
  for (int i = 0; i < 4; i++)
#pragma unroll
    for (int j = 0; j < 2; j++) acc[i][j] = (f32x4){0.f, 0.f, 0.f, 0.f};

  for (int k0 = 0; k0 < EMB; k0 += 32) {
    __syncthreads();
    gload16(Ag + k0, Asl);
    gload16(Ag + (size_t)16 * EMB + k0, Asl + 512);
    gload16(Bg + k0, Bsl);
    __syncthreads();
    f16x8 af[4], bf[2];
#pragma unroll
    for (int mi = 0; mi < 4; mi++) af[mi] = *(const f16x8*)&As[aoff[mi]];
#pragma unroll
    for (int ni = 0; ni < 2; ni++) bf[ni] = *(const f16x8*)&Bs[boff[ni]];
#pragma unroll
    for (int mi = 0; mi < 4; mi++)
#pragma unroll
      for (int ni = 0; ni < 2; ni++)
        acc[mi][ni] = __builtin_amdgcn_mfma_f32_16x16x32_f16(af[mi], bf[ni], acc[mi][ni], 0, 0, 0);
  }

#pragma unroll
  for (int mi = 0; mi < 4; mi++) {
#pragma unroll
    for (int ni = 0; ni < 2; ni++) {
      int row0 = bm + wm + mi * 16 + quad * 4;
      int col = bn + wn + ni * 16 + l16;
#pragma unroll
      for (int rg = 0; rg < 4; rg++)
        C[(size_t)(row0 + rg) * EMB + col] = acc[mi][ni][rg];
    }
  }
}

// ---------------- Differential attention v8: both halves per wave ----------------
// 256 threads, 4 waves = (qs=wave&1? no: wave = qs*2+ks). wave -> (qs=wave>>1, ks=wave&1):
// 32 q-rows (qs), one 32-key half (ks) of each 64-key tile, BOTH hh halves.
// V fragment read once feeds both halves' PV MFMAs (V DS reads halved vs v6);
// differential combine + RMS-norm fully in-wave (no epilogue LDS bounce/barriers).
// Grid (h 16, qblk 32) = 512 blocks, 2/CU (64 KB LDS).
// Ks tile T=kb*8+c: entry[l*8+j] = K[kb*32+(l&31)][c*16+(l>>5)*8+j]   (c spans 128 dims)
// Vt tile T=kc*4+dt: entry[l*8+j] = V[kc*16+(l>>5)*8+j][dt*32+(l&31)]
// QK^T via mfma_32x32x16_f16 (S^T: col=lane&31=q, row=(r&3)+8*(r>>2)+4*hi=key);
// P -> bf16 PV B-frags in registers via v_cvt_pk_bf16_f32 + permlane32_swap.
__global__ __launch_bounds__(256, 2) void diff_attn_v8(
    const f16* __restrict__ qb, const f16* __restrict__ kb, const ushort_t* __restrict__ vbT,
    const float* __restrict__ lq1, const float* __restrict__ lq2,
    const float* __restrict__ lk1, const float* __restrict__ lk2,
    const float* __restrict__ subw, f16* __restrict__ attnb) {
  const int h = blockIdx.x;  // head fastest -> heads stay L2-resident per XCD
  const int qblk = blockIdx.y;
  const int tid = threadIdx.x;
  const int wave = tid >> 6, lane = tid & 63;
  const int l32 = lane & 31, hi = lane >> 5;
  const int qs = wave >> 1, ks = wave & 1;

  __shared__ f16 Ks[2][8192];       // 2 x 16 KB (64 keys x 128 dims per buf)
  __shared__ ushort_t Vt[2][8192];  // 2 x 16 KB

  // ---- Q B-frags for BOTH halves (q pre-scaled by sqrt(128)*log2e at rope) ----
  const int qrow0 = qblk * 64 + qs * 32;
  f16x8 qf[2][4];  // [hh][c]
#pragma unroll
  for (int hh = 0; hh < 2; hh++)
#pragma unroll
    for (int c = 0; c < 4; c++)
      qf[hh][c] = *(const f16x8*)(qb + (size_t)(qrow0 + l32) * EMB + h * 128 + hh * 64 +
                                  c * 16 + hi * 8);

  f32x16 O0[4], O1[4];  // [dim-tile] per half; col=q=l32, row=(r&3)+8*(r>>2)+4*hi
#pragma unroll
  for (int dt = 0; dt < 4; dt++)
#pragma unroll
    for (int s2 = 0; s2 < 16; s2++) {
      O0[dt][s2] = 0.f;
      O1[dt][s2] = 0.f;
    }
  float lsum0 = 0.f, lsum1 = 0.f;

  // ---- staging source addresses (per-lane swizzled global, linear LDS dest) ----
  // wave w stages K tiles w*4+j2 (kb=w>>1, c=(w&1)*4+j2) and V chunk w*2048+j2*512
  const f16* kgp =
      kb + (size_t)((wave >> 1) * 32 + l32) * EMB + h * 128 + (wave & 1) * 64 + hi * 8;
  const ushort_t* vgp = vbT + (size_t)h * 262144 + (size_t)wave * 2048 + lane * 8;

  auto stage = [&](int buf, int it) {
#pragma unroll
    for (int j2 = 0; j2 < 4; j2++)
      gload16(kgp + (size_t)it * (64 * EMB) + j2 * 16, &Ks[buf][(wave * 4 + j2) * 512]);
#pragma unroll
    for (int j2 = 0; j2 < 4; j2++)
      gload16(vgp + (size_t)it * 8192 + j2 * 512, &Vt[buf][(wave * 4 + j2) * 512]);
  };

  // ---- initial tile 0 into buf 0 ----
  stage(0, 0);
  __syncthreads();

  auto step = [&](int cbuf, int nit) {
    if (nit < 32) stage(cbuf ^ 1, nit);  // async, lands before next barrier

    const f16* KsC = &Ks[cbuf][0];
    const ushort_t* VtC = &Vt[cbuf][0];

    // ---- S^T = K·Q^T for this wave's 32-key half, both hh (independent chains) ----
    f32x16 acc0, acc1;
#pragma unroll
    for (int s2 = 0; s2 < 16; s2++) {
      acc0[s2] = -28.8539008f;  // softmax bias in C-init
      acc1[s2] = -28.8539008f;
    }
#pragma unroll
    for (int c = 0; c < 4; c++) {
      f16x8 kf = *(const f16x8*)&KsC[(ks * 8 + c) * 512 + lane * 8];
      acc0 = __builtin_amdgcn_mfma_f32_32x32x16_f16(kf, qf[0][c], acc0, 0, 0, 0);
    }
#pragma unroll
    for (int c = 0; c < 4; c++) {
      f16x8 kf = *(const f16x8*)&KsC[(ks * 8 + 4 + c) * 512 + lane * 8];
      acc1 = __builtin_amdgcn_mfma_f32_32x32x16_f16(kf, qf[1][c], acc1, 0, 0, 0);
    }

    // ---- exp2 + pack to bf16 PV B-frags (exp2(hh0) overlaps acc1's MFMAs) ----
    bf16x8 pf[2][2];  // [hh][c2]
#pragma unroll
    for (int hh = 0; hh < 2; hh++) {
      float p[16];
#pragma unroll
      for (int s2 = 0; s2 < 16; s2++)
        p[s2] = __builtin_exp2f(hh ? acc1[s2] : acc0[s2]);
      float ls = (((p[0] + p[1]) + (p[2] + p[3])) + ((p[4] + p[5]) + (p[6] + p[7]))) +
                 (((p[8] + p[9]) + (p[10] + p[11])) + ((p[12] + p[13]) + (p[14] + p[15])));
      if (hh == 0) lsum0 += ls; else lsum1 += ls;
#pragma unroll
      for (int c2 = 0; c2 < 2; c2++) {
        unsigned w0 = cvt_pk_bf16_2(p[8 * c2 + 0], p[8 * c2 + 1]);
        unsigned w1 = cvt_pk_bf16_2(p[8 * c2 + 2], p[8 * c2 + 3]);
        unsigned w2 = cvt_pk_bf16_2(p[8 * c2 + 4], p[8 * c2 + 5]);
        unsigned w3 = cvt_pk_bf16_2(p[8 * c2 + 6], p[8 * c2 + 7]);
        asm("v_permlane32_swap_b32 %0, %1" : "+v"(w0), "+v"(w2));
        asm("v_permlane32_swap_b32 %0, %1" : "+v"(w1), "+v"(w3));
        uint4v pw;
        pw.x = w0; pw.y = w1; pw.z = w2; pw.w = w3;
        pf[hh][c2] = __builtin_bit_cast(bf16x8, pw);
      }
    }

    // ---- O += V * P: each V fragment read once, feeds BOTH halves ----
    __builtin_amdgcn_s_setprio(1);
#pragma unroll
    for (int c2 = 0; c2 < 2; c2++) {
#pragma unroll
      for (int dt = 0; dt < 4; dt++) {
        bf16x8 vf = *(const bf16x8*)&VtC[((ks * 2 + c2) * 4 + dt) * 512 + lane * 8];
        O0[dt] = __builtin_amdgcn_mfma_f32_32x32x16_bf16(vf, pf[0][c2], O0[dt], 0, 0, 0);
        O1[dt] = __builtin_amdgcn_mfma_f32_32x32x16_bf16(vf, pf[1][c2], O1[dt], 0, 0, 0);
      }
    }
    __builtin_amdgcn_s_setprio(0);
    __syncthreads();
  };

  for (int it = 0; it < 32; it += 2) {
    step(0, it + 1);
    step(1, it + 2);
  }

  // ---- lambda ----
  float d1 = 0.f, d2 = 0.f;
  for (int i = 0; i < 64; i++) {
    d1 += lq1[i] * lk1[i];
    d2 += lq2[i] * lk2[i];
  }
  const float lam = __expf(d1) - __expf(d2) + 0.783605767f;

  // ---- per-q denominators: this wave + partner-ks wave? No: ks-halves are per-wave
  // partial over keys; lanes hi=0/1 cover disjoint key chunks -> shfl; then the two
  // ks waves hold partial sums over DIFFERENT keys of the SAME q rows -> combine via
  // LDS (small: 2 halves x 2 qs x 2 ks x 32 q floats) ----
  __shared__ float lsb[2][2][2][32];  // [hh][qs][ks][q]
  {
    float s0 = lsum0 + __shfl_xor(lsum0, 32);
    float s1 = lsum1 + __shfl_xor(lsum1, 32);
    if (hi == 0) {
      lsb[0][qs][ks][l32] = s0;
      lsb[1][qs][ks][l32] = s1;
    }
  }
  __syncthreads();
  const float den0 = lsb[0][qs][0][l32] + lsb[0][qs][1][l32];
  const float den1 = lsb[1][qs][0][l32] + lsb[1][qs][1][l32];
  const float inv0 = 1.f / den0;
  const float inv1 = lam / den1;

  // ---- partial differential O for this ks-half; combine ks-halves via LDS ----
  // Each ks wave holds partial O (over its 1024 keys). a_partial = O0*inv0 - O1*inv1
  // is linear -> sum partials. ks=1 publishes, ks=0 merges, then in-wave RMS + store.
  float* Obuf = (float*)&Ks[0][0];  // 16384 floats; region per qs: 8192 floats
#pragma unroll
  for (int dt = 0; dt < 4; dt++)
#pragma unroll
    for (int s2 = 0; s2 < 16; s2++) O0[dt][s2] = O0[dt][s2] * inv0 - O1[dt][s2] * inv1;

  if (ks == 1) {
#pragma unroll
    for (int dt = 0; dt < 4; dt++)
#pragma unroll
      for (int rq = 0; rq < 4; rq++) {
        f32x4 v;
#pragma unroll
        for (int rg = 0; rg < 4; rg++) v[rg] = O0[dt][rq * 4 + rg];
        *(f32x4*)&Obuf[(qs * 8192) + (dt * 4 + rq) * 256 + lane * 4] = v;
      }
  }
  __syncthreads();
  if (ks == 0) {
    float ms = 0.f;
#pragma unroll
    for (int dt = 0; dt < 4; dt++)
#pragma unroll
      for (int rq = 0; rq < 4; rq++) {
        f32x4 v1 = *(const f32x4*)&Obuf[(qs * 8192) + (dt * 4 + rq) * 256 + lane * 4];
#pragma unroll
        for (int rg = 0; rg < 4; rg++) {
          float v = O0[dt][rq * 4 + rg] + v1[rg];
          O0[dt][rq * 4 + rg] = v;
          ms += v * v;
        }
      }
    ms += __shfl_xor(ms, 32);
    const float rms = rsqrtf(ms * (1.f / 128.f) + 1e-5f);
    const int t_g = qrow0 + l32;
#pragma unroll
    for (int dt = 0; dt < 4; dt++)
#pragma unroll
      for (int rq = 0; rq < 4; rq++) {
        f32x4 sw = *(const f32x4*)(subw + dt * 32 + rq * 8 + hi * 4);
        f16x4 o;
#pragma unroll
        for (int rg = 0; rg < 4; rg++) o[rg] = (f16)(O0[dt][rq * 4 + rg] * rms * sw[rg]);
        *(f16x4*)(attnb + (size_t)t_g * EMB + h * 128 + dt * 32 + rq * 8 + hi * 4) = o;
      }
  }
}

// ---------------- launcher ----------------
extern "C" void kernel_launch(void* const* d_in, const int* in_sizes, int n_in,
                              void* d_out, int out_size, void* d_ws, size_t ws_size,
                              hipStream_t stream) {
  const float* x    = (const float*)d_in[0];
  const float* wq   = (const float*)d_in[1];
  const float* wk   = (const float*)d_in[2];
  const float* wv   = (const float*)d_in[3];
  const float* wout = (const float*)d_in[4];
  const float* lq1  = (const float*)d_in[5];
  const float* lq2  = (const float*)d_in[6];
  const float* lk1  = (const float*)d_in[7];
  const float* lk2  = (const float*)d_in[8];
  const float* subw = (const float*)d_in[9];
  float* out = (float*)d_out;

  char* ws = (char*)d_ws;
  const size_t MB = 1024 * 1024;
  f16* xb    = (f16*)(ws + 0 * MB);
  f16* wqb   = (f16*)(ws + 8 * MB);
  f16* wkb   = (f16*)(ws + 16 * MB);
  f16* wvb   = (f16*)(ws + 24 * MB);
  f16* woutb = (f16*)(ws + 32 * MB);
  f16* qb    = (f16*)(ws + 40 * MB);
  f16* kb    = (f16*)(ws + 48 * MB);
  ushort_t* vbT = (ushort_t*)(ws + 56 * MB);  // bf16, 32x32-fragment-tiled per head
  f16* attnb = (f16*)(ws + 64 * MB);
  float* cosT = (float*)(ws + 72 * MB);
  float* sinT = (float*)(ws + 72 * MB + 262144);

  dim3 b256(256);
  cvt5_kernel<<<5 * 4096, b256, 0, stream>>>(x, wq, wk, wv, wout, xb, wqb, wkb, wvb, woutb);
  rope_table_kernel<<<256, b256, 0, stream>>>(cosT, sinT);

  proj_gemm_kernel<<<dim3(16, 16, 3), b256, 0, stream>>>(xb, wqb, wkb, wvb, qb, kb, vbT);

  rope2_kernel<<<dim3(8192, 2), b256, 0, stream>>>(qb, kb, cosT, sinT);

  diff_attn_v8<<<dim3(16, 32), b256, 0, stream>>>(qb, kb, vbT, lq1, lq2, lk1, lk2, subw, attnb);

  out_gemm_kernel<<<dim3(32, 16), b256, 0, stream>>>(attnb, woutb, out);
}

// Round 5
// 296.835 us; speedup vs baseline: 1.2703x; 1.0244x over previous
//
#include <hip/hip_runtime.h>
#include <math.h>

#define SEQ 2048
#define EMB 2048

typedef _Float16 f16;
typedef unsigned short ushort_t;
typedef __attribute__((ext_vector_type(2))) _Float16 f16x2;
typedef __attribute__((ext_vector_type(4))) _Float16 f16x4;
typedef __attribute__((ext_vector_type(8))) _Float16 f16x8;
typedef __attribute__((ext_vector_type(4))) float f32x4;
typedef __attribute__((ext_vector_type(16))) float f32x16;
typedef __attribute__((ext_vector_type(8))) short bf16x8;
typedef __attribute__((ext_vector_type(4))) unsigned short us4;
typedef __attribute__((ext_vector_type(8))) unsigned short us8;
typedef __attribute__((ext_vector_type(4))) unsigned int uint4v;

// async global->LDS, 16B per lane; LDS dest is lane-contiguous from lane0's ptr
__device__ __forceinline__ void gload16(const void* g, void* l) {
  __builtin_amdgcn_global_load_lds((const __attribute__((address_space(1))) unsigned int*)g,
                                   (__attribute__((address_space(3))) unsigned int*)l, 16, 0, 0);
}

__device__ __forceinline__ ushort_t f32_to_bf16(float f) {
  unsigned int u = __builtin_bit_cast(unsigned int, f);
  u += 0x7FFFu + ((u >> 16) & 1u);
  return (ushort_t)(u >> 16);
}

// packed f32x2 -> bf16x2 in one VALU op (RNE)
__device__ __forceinline__ unsigned cvt_pk_bf16_2(float lo, float hi) {
  unsigned r;
  asm("v_cvt_pk_bf16_f32 %0, %1, %2" : "=v"(r) : "v"(lo), "v"(hi));
  return r;
}

// ---------------- fp32 -> fp16 conversion, 5 tensors in one launch ----------------
__global__ __launch_bounds__(256) void cvt5_kernel(const float* __restrict__ i0,
                                                   const float* __restrict__ i1,
                                                   const float* __restrict__ i2,
                                                   const float* __restrict__ i3,
                                                   const float* __restrict__ i4,
                                                   f16* __restrict__ o0, f16* __restrict__ o1,
                                                   f16* __restrict__ o2, f16* __restrict__ o3,
                                                   f16* __restrict__ o4) {
  int b = blockIdx.x;
  int z = b >> 12;
  const float* in = (z == 0) ? i0 : (z == 1) ? i1 : (z == 2) ? i2 : (z == 3) ? i3 : i4;
  f16* out = (z == 0) ? o0 : (z == 1) ? o1 : (z == 2) ? o2 : (z == 3) ? o3 : o4;
  int i = ((b & 4095) * 256 + threadIdx.x) * 4;
  f32x4 v = *(const f32x4*)(in + i);
  *(f16x4*)(out + i) = __builtin_convertvector(v, f16x4);
}

// ---------------- RoPE tables (double precision, matches numpy) ----------------
__global__ __launch_bounds__(256) void rope_table_kernel(float* __restrict__ cosT,
                                                         float* __restrict__ sinT) {
  int id = blockIdx.x * 256 + threadIdx.x;
  int t = id >> 5, i = id & 31;
  double inv = pow(10000.0, -(double)i / 32.0);
  double ang = (double)t * inv;
  cosT[id] = (float)cos(ang);
  sinT[id] = (float)sin(ang);
}

// ---------------- Fused projection GEMM + RoPE epilogue, BK=32, swizzled LDS --------
// z=0->q f16 (rope + sqrt(128)*log2e scale), z=1->k f16 (rope),
// z=2->v bf16 fragment-tiled vbT for 32x32x16 PV:
// vbT index for V[t][h*128+d] (kb=t>>6, kc=(t>>4)&3, hi8=(t>>3)&1, j=t&7, dt=d>>5, dr=d&31):
//   (((h*32+kb)*4+kc)*4+dt)*512 + (hi8*32+dr)*8 + j
// RoPE in epilogue: pair (2i,2i+1) = adjacent output cols = adjacent l16 lanes ->
// partner value via __shfl_xor(.,1); cos/sin from f32 tables (f64-accurate).
__global__ __launch_bounds__(256, 3) void proj_gemm_kernel(
    const f16* __restrict__ A, const f16* __restrict__ B0, const f16* __restrict__ B1,
    const f16* __restrict__ B2, const float* __restrict__ cosT, const float* __restrict__ sinT,
    f16* __restrict__ qout, f16* __restrict__ kout, ushort_t* __restrict__ vtout) {
  const int z = blockIdx.z;
  const f16* __restrict__ B = (z == 0) ? B0 : ((z == 1) ? B1 : B2);
  __shared__ f16 As[128 * 32];
  __shared__ f16 Bs[128 * 32];
  const int tid = threadIdx.x;
  const int wave = tid >> 6, lane = tid & 63;
  const int l16 = lane & 15, quad = lane >> 4;
  const int wm = (wave >> 1) << 6, wn = (wave & 1) << 6;
  const int bm = blockIdx.y << 7, bn = blockIdx.x << 7;

  const int swg = ((lane & 3) ^ ((lane >> 3) & 3)) * 8;
  const f16* Ag = A + (size_t)(bm + wave * 32 + (lane >> 2)) * EMB + swg;
  const f16* Bg = B + (size_t)(bn + wave * 32 + (lane >> 2)) * EMB + swg;
  f16* Asl = &As[wave * 1024 + lane * 8];
  f16* Bsl = &Bs[wave * 1024 + lane * 8];

  const int swr = (quad ^ ((l16 >> 1) & 3)) * 8;
  int aoff[4], boff[4];
#pragma unroll
  for (int i = 0; i < 4; i++) {
    aoff[i] = (wm + i * 16 + l16) * 32 + swr;
    boff[i] = (wn + i * 16 + l16) * 32 + swr;
  }

  f32x4 acc[4][4];
#pragma unroll
  for (int i = 0; i < 4; i++)
#pragma unroll
    for (int j = 0; j < 4; j++) acc[i][j] = (f32x4){0.f, 0.f, 0.f, 0.f};

  for (int k0 = 0; k0 < EMB; k0 += 32) {
    __syncthreads();
    gload16(Ag + k0, Asl);
    gload16(Ag + (size_t)16 * EMB + k0, Asl + 512);
    gload16(Bg + k0, Bsl);
    gload16(Bg + (size_t)16 * EMB + k0, Bsl + 512);
    __syncthreads();
    f16x8 af[4], bf[4];
#pragma unroll
    for (int mi = 0; mi < 4; mi++) af[mi] = *(const f16x8*)&As[aoff[mi]];
#pragma unroll
    for (int ni = 0; ni < 4; ni++) bf[ni] = *(const f16x8*)&Bs[boff[ni]];
#pragma unroll
    for (int mi = 0; mi < 4; mi++)
#pragma unroll
      for (int ni = 0; ni < 4; ni++)
        acc[mi][ni] = __builtin_amdgcn_mfma_f32_16x16x32_f16(af[mi], bf[ni], acc[mi][ni], 0, 0, 0);
  }

  if (z == 2) {
#pragma unroll
    for (int mi = 0; mi < 4; mi++) {
#pragma unroll
      for (int ni = 0; ni < 4; ni++) {
        int row0 = bm + wm + mi * 16 + quad * 4;  // C/D: col=l16, row=quad*4+reg
        int col = bn + wn + ni * 16 + l16;
        us4 o;
#pragma unroll
        for (int rg = 0; rg < 4; rg++) o[rg] = f32_to_bf16(acc[mi][ni][rg]);
        int hidx = col >> 7, d = col & 127, t = row0;  // t..t+3 share all bits above t&7
        size_t idx = ((((size_t)hidx * 32 + (t >> 6)) * 4 + ((t >> 4) & 3)) * 4 + (d >> 5)) * 512 +
                     (((t >> 3) & 1) * 32 + (d & 31)) * 8 + (t & 7);
        *(us4*)&vtout[idx] = o;
      }
    }
  } else {
    f16* Co = (z == 0) ? qout : kout;
    const float scale = (z == 0) ? 16.3222307f : 1.0f;  // sqrt(128)*log2(e) folded into q
#pragma unroll
    for (int mi = 0; mi < 4; mi++) {
#pragma unroll
      for (int ni = 0; ni < 4; ni++) {
        int row0 = bm + wm + mi * 16 + quad * 4;
        int col = bn + wn + ni * 16 + l16;
        int i_r = (col & 63) >> 1;
        int odd = col & 1;  // = l16 & 1 (bn, wn, ni*16 even)
#pragma unroll
        for (int rg = 0; rg < 4; rg++) {
          int t = row0 + rg;
          float c = cosT[(t << 5) + i_r] * scale;
          float s = sinT[(t << 5) + i_r] * scale;
          float own = acc[mi][ni][rg];
          float other = __shfl_xor(own, 1);
          float xr = odd ? other : own;
          float xi = odd ? own : other;
          float outv = odd ? (xr * s + xi * c) : (xr * c - xi * s);
          Co[(size_t)t * EMB + col] = (f16)outv;
        }
      }
    }
  }
}

// ---------------- Output GEMM: C = attn * wout^T, f32 out, 128x64 tiles, BK=32 ----------
__global__ __launch_bounds__(256, 2) void out_gemm_kernel(const f16* __restrict__ A,
                                                          const f16* __restrict__ B,
                                                          float* __restrict__ C) {
  __shared__ f16 As[128 * 32];
  __shared__ f16 Bs[64 * 32];
  const int tid = threadIdx.x;
  const int wave = tid >> 6, lane = tid & 63;
  const int l16 = lane & 15, quad = lane >> 4;
  const int wm = (wave >> 1) << 6, wn = (wave & 1) << 5;
  const int bm = blockIdx.y << 7, bn = blockIdx.x << 6;

  const int swg = ((lane & 3) ^ ((lane >> 3) & 3)) * 8;
  const f16* Ag = A + (size_t)(bm + wave * 32 + (lane >> 2)) * EMB + swg;
  const f16* Bg = B + (size_t)(bn + wave * 16 + (lane >> 2)) * EMB + swg;
  f16* Asl = &As[wave * 1024 + lane * 8];
  f16* Bsl = &Bs[wave * 512 + lane * 8];

  const int swr = (quad ^ ((l16 >> 1) & 3)) * 8;
  int aoff[4], boff[2];
#pragma unroll
  for (int i = 0; i < 4; i++) aoff[i] = (wm + i * 16 + l16) * 32 + swr;
#pragma unroll
  for (int i = 0; i < 2; i++) boff[i] = (wn + i * 16 + l16) * 32 + swr;

  f32x4 acc[4][2];
#pragma unroll
  for (int i = 0; i < 4; i++)
#pragma unroll
    for (int j = 0; j < 2; j++) acc[i][j] = (f32x4){0.f, 0.f, 0.f, 0.f};

  for (int k0 = 0; k0 < EMB; k0 += 32) {
    __syncthreads();
    gload16(Ag + k0, Asl);
    gload16(Ag + (size_t)16 * EMB + k0, Asl + 512);
    gload16(Bg + k0, Bsl);
    __syncthreads();
    f16x8 af[4], bf[2];
#pragma unroll
    for (int mi = 0; mi < 4; mi++) af[mi] = *(const f16x8*)&As[aoff[mi]];
#pragma unroll
    for (int ni = 0; ni < 2; ni++) bf[ni] = *(const f16x8*)&Bs[boff[ni]];
#pragma unroll
    for (int mi = 0; mi < 4; mi++)
#pragma unroll
      for (int ni = 0; ni < 2; ni++)
        acc[mi][ni] = __builtin_amdgcn_mfma_f32_16x16x32_f16(af[mi], bf[ni], acc[mi][ni], 0, 0, 0);
  }

#pragma unroll
  for (int mi = 0; mi < 4; mi++) {
#pragma unroll
    for (int ni = 0; ni < 2; ni++) {
      int row0 = bm + wm + mi * 16 + quad * 4;
      int col = bn + wn + ni * 16 + l16;
#pragma unroll
      for (int rg = 0; rg < 4; rg++)
        C[(size_t)(row0 + rg) * EMB + col] = acc[mi][ni][rg];
    }
  }
}

// ---------------- Differential attention v9: v6 + in-wave software pipeline --------
// 256 threads, 4 waves = (hh=wave>>1, qs=wave&1), 32 q-rows per wave, 64 per block.
// Grid (h 16, qblk 32) = 512 blocks, 2/CU (64 KB LDS).
// Step order pipelined: QK(kbi0) -> QK(kbi1) [indep chains] -> exp/pack(kbi0)
// [hides QK1 retire] -> PV(kc0,1) -> exp/pack(kbi1) [VALU hides under PV MFMAs]
// -> PV(kc2,3). Staging via global_load_lds, double-buffered, in flight across
// the whole compute phase.
// Ks tile T=hh*8+kbi*4+c: entry[l*8+j] = K[kbi*32+(l&31)][hh*64+c*16+(l>>5)*8+j]
// Vt tile T=kc*4+dt:      entry[l*8+j] = V[kc*16+(l>>5)*8+j][dt*32+(l&31)]
__global__ __launch_bounds__(256, 2) void diff_attn_v9(
    const f16* __restrict__ qb, const f16* __restrict__ kb, const ushort_t* __restrict__ vbT,
    const float* __restrict__ lq1, const float* __restrict__ lq2,
    const float* __restrict__ lk1, const float* __restrict__ lk2,
    const float* __restrict__ subw, f16* __restrict__ attnb) {
  const int h = blockIdx.x;  // head fastest -> heads stay L2-resident per XCD
  const int qblk = blockIdx.y;
  const int tid = threadIdx.x;
  const int wave = tid >> 6, lane = tid & 63;
  const int l32 = lane & 31, hi = lane >> 5;
  const int hh = wave >> 1, qs = wave & 1;

  __shared__ f16 Ks[2][8192];       // 2 x 16 KB (64 keys x 128 dims per buf)
  __shared__ ushort_t Vt[2][8192];  // 2 x 16 KB

  // ---- Q B-frags (q pre-scaled by sqrt(128)*log2e at proj): col=q=l32, k=hi*8+j ----
  const int qrow0 = qblk * 64 + qs * 32;
  f16x8 qf[4];
#pragma unroll
  for (int c = 0; c < 4; c++)
    qf[c] = *(const f16x8*)(qb + (size_t)(qrow0 + l32) * EMB + h * 128 + hh * 64 + c * 16 + hi * 8);

  f32x16 O[4];  // [dim-tile]; col=q=l32, row=(r&3)+8*(r>>2)+4*hi = dim within tile
#pragma unroll
  for (int dt = 0; dt < 4; dt++)
#pragma unroll
    for (int s2 = 0; s2 < 16; s2++) O[dt][s2] = 0.f;
  float lsum = 0.f;

  // ---- staging source addresses (per-lane swizzled global, linear LDS dest) ----
  const int hhs = wave >> 1, kbs = wave & 1;
  const f16* kgp = kb + (size_t)(kbs * 32 + l32) * EMB + h * 128 + hhs * 64 + hi * 8;
  const ushort_t* vgp = vbT + ((size_t)h * 32) * 8192 + (size_t)wave * 2048 + lane * 8;

  auto stage = [&](int buf, int it) {
#pragma unroll
    for (int j2 = 0; j2 < 4; j2++)
      gload16(kgp + (size_t)it * (64 * EMB) + j2 * 16, &Ks[buf][(wave * 4 + j2) * 512]);
#pragma unroll
    for (int j2 = 0; j2 < 4; j2++)
      gload16(vgp + (size_t)it * 8192 + j2 * 512, &Vt[buf][(wave * 4 + j2) * 512]);
  };

  // ---- initial tile 0 into buf 0 ----
  stage(0, 0);
  __syncthreads();

  auto qk4 = [&](const f16* KsC, int kbi) {
    f32x16 acc;
#pragma unroll
    for (int s2 = 0; s2 < 16; s2++) acc[s2] = -28.8539008f;  // softmax bias in C-init
#pragma unroll
    for (int c = 0; c < 4; c++) {
      f16x8 kf = *(const f16x8*)&KsC[(hh * 8 + kbi * 4 + c) * 512 + lane * 8];
      acc = __builtin_amdgcn_mfma_f32_32x32x16_f16(kf, qf[c], acc, 0, 0, 0);
    }
    return acc;
  };

  auto exppack = [&](const f32x16& acc, bf16x8* pf2) {
    float p[16];
#pragma unroll
    for (int s2 = 0; s2 < 16; s2++) p[s2] = __builtin_exp2f(acc[s2]);
    lsum += (((p[0] + p[1]) + (p[2] + p[3])) + ((p[4] + p[5]) + (p[6] + p[7]))) +
            (((p[8] + p[9]) + (p[10] + p[11])) + ((p[12] + p[13]) + (p[14] + p[15])));
#pragma unroll
    for (int c2 = 0; c2 < 2; c2++) {
      unsigned w0 = cvt_pk_bf16_2(p[8 * c2 + 0], p[8 * c2 + 1]);
      unsigned w1 = cvt_pk_bf16_2(p[8 * c2 + 2], p[8 * c2 + 3]);
      unsigned w2 = cvt_pk_bf16_2(p[8 * c2 + 4], p[8 * c2 + 5]);
      unsigned w3 = cvt_pk_bf16_2(p[8 * c2 + 6], p[8 * c2 + 7]);
      asm("v_permlane32_swap_b32 %0, %1" : "+v"(w0), "+v"(w2));
      asm("v_permlane32_swap_b32 %0, %1" : "+v"(w1), "+v"(w3));
      uint4v pw;
      pw.x = w0; pw.y = w1; pw.z = w2; pw.w = w3;
      pf2[c2] = __builtin_bit_cast(bf16x8, pw);
    }
  };

  auto pv2 = [&](const ushort_t* VtC, int kc0, const bf16x8* pf2) {
#pragma unroll
    for (int c2 = 0; c2 < 2; c2++) {
#pragma unroll
      for (int dt = 0; dt < 4; dt++) {
        bf16x8 vf = *(const bf16x8*)&VtC[((kc0 + c2) * 4 + dt) * 512 + lane * 8];
        O[dt] = __builtin_amdgcn_mfma_f32_32x32x16_bf16(vf, pf2[c2], O[dt], 0, 0, 0);
      }
    }
  };

  auto step = [&](int cbuf, int nit) {
    if (nit < 32) stage(cbuf ^ 1, nit);  // async, lands before next barrier

    const f16* KsC = &Ks[cbuf][0];
    const ushort_t* VtC = &Vt[cbuf][0];

    // pipelined order: both QK chains issued first; exp/pack(0) while QK1 retires;
    // PV(kc0,1) issued; exp/pack(1) VALU hides under those MFMAs; PV(kc2,3).
    f32x16 acc0 = qk4(KsC, 0);
    f32x16 acc1 = qk4(KsC, 1);
    bf16x8 pfa[2], pfb[2];
    exppack(acc0, pfa);
    __builtin_amdgcn_s_setprio(1);
    pv2(VtC, 0, pfa);
    __builtin_amdgcn_s_setprio(0);
    exppack(acc1, pfb);
    __builtin_amdgcn_s_setprio(1);
    pv2(VtC, 2, pfb);
    __builtin_amdgcn_s_setprio(0);
    __syncthreads();
  };

  for (int it = 0; it < 32; it += 2) {
    step(0, it + 1);
    step(1, it + 2);
  }

  // ---- lambda ----
  float d1 = 0.f, d2 = 0.f;
  for (int i = 0; i < 64; i++) {
    d1 += lq1[i] * lk1[i];
    d2 += lq2[i] * lk2[i];
  }
  const float lam = __expf(d1) - __expf(d2) + 0.783605767f;

  // ---- per-q softmax denominator (lane + partner lane cover all keys) ----
  float s = lsum + __shfl_xor(lsum, 32);
  const float inv = (hh == 0) ? (1.f / s) : (lam / s);

  // ---- cross-half combine through LDS (reuse Ks area, 32 KB) ----
  float* Obuf = (float*)&Ks[0][0];
  if (hh == 1) {
#pragma unroll
    for (int dt = 0; dt < 4; dt++)
#pragma unroll
      for (int rq = 0; rq < 4; rq++) {
        f32x4 v;
#pragma unroll
        for (int rg = 0; rg < 4; rg++) v[rg] = O[dt][rq * 4 + rg] * inv;
        *(f32x4*)&Obuf[(((qs * 4 + dt) * 4 + rq) * 64 + lane) * 4] = v;
      }
  }
  __syncthreads();
  if (hh == 0) {
    float a[4][16];
    float ms = 0.f;
#pragma unroll
    for (int dt = 0; dt < 4; dt++)
#pragma unroll
      for (int rq = 0; rq < 4; rq++) {
        f32x4 o1 = *(const f32x4*)&Obuf[(((qs * 4 + dt) * 4 + rq) * 64 + lane) * 4];
#pragma unroll
        for (int rg = 0; rg < 4; rg++) {
          float v = O[dt][rq * 4 + rg] * inv - o1[rg];
          a[dt][rq * 4 + rg] = v;
          ms += v * v;
        }
      }
    ms += __shfl_xor(ms, 32);
    const float rms = rsqrtf(ms * (1.f / 128.f) + 1e-5f);
    const int t_g = qrow0 + l32;
#pragma unroll
    for (int dt = 0; dt < 4; dt++)
#pragma unroll
      for (int rq = 0; rq < 4; rq++) {
        f32x4 sw = *(const f32x4*)(subw + dt * 32 + rq * 8 + hi * 4);
        f16x4 o;
#pragma unroll
        for (int rg = 0; rg < 4; rg++) o[rg] = (f16)(a[dt][rq * 4 + rg] * rms * sw[rg]);
        *(f16x4*)(attnb + (size_t)t_g * EMB + h * 128 + dt * 32 + rq * 8 + hi * 4) = o;
      }
  }
}

// ---------------- launcher ----------------
extern "C" void kernel_launch(void* const* d_in, const int* in_sizes, int n_in,
                              void* d_out, int out_size, void* d_ws, size_t ws_size,
                              hipStream_t stream) {
  const float* x    = (const float*)d_in[0];
  const float* wq   = (const float*)d_in[1];
  const float* wk   = (const float*)d_in[2];
  const float* wv   = (const float*)d_in[3];
  const float* wout = (const float*)d_in[4];
  const float* lq1  = (const float*)d_in[5];
  const float* lq2  = (const float*)d_in[6];
  const float* lk1  = (const float*)d_in[7];
  const float* lk2  = (const float*)d_in[8];
  const float* subw = (const float*)d_in[9];
  float* out = (float*)d_out;

  char* ws = (char*)d_ws;
  const size_t MB = 1024 * 1024;
  f16* xb    = (f16*)(ws + 0 * MB);
  f16* wqb   = (f16*)(ws + 8 * MB);
  f16* wkb   = (f16*)(ws + 16 * MB);
  f16* wvb   = (f16*)(ws + 24 * MB);
  f16* woutb = (f16*)(ws + 32 * MB);
  f16* qb    = (f16*)(ws + 40 * MB);
  f16* kb    = (f16*)(ws + 48 * MB);
  ushort_t* vbT = (ushort_t*)(ws + 56 * MB);  // bf16, 32x32-fragment-tiled per head
  f16* attnb = (f16*)(ws + 64 * MB);
  float* cosT = (float*)(ws + 72 * MB);
  float* sinT = (float*)(ws + 72 * MB + 262144);

  dim3 b256(256);
  cvt5_kernel<<<5 * 4096, b256, 0, stream>>>(x, wq, wk, wv, wout, xb, wqb, wkb, wvb, woutb);
  rope_table_kernel<<<256, b256, 0, stream>>>(cosT, sinT);

  proj_gemm_kernel<<<dim3(16, 16, 3), b256, 0, stream>>>(xb, wqb, wkb, wvb, cosT, sinT, qb, kb,
                                                         vbT);

  diff_attn_v9<<<dim3(16, 32), b256, 0, stream>>>(qb, kb, vbT, lq1, lq2, lk1, lk2, subw, attnb);

  out_gemm_kernel<<<dim3(32, 16), b256, 0, stream>>>(attnb, woutb, out);
}